// Round 6
// baseline (216.431 us; speedup 1.0000x reference)
//
#include <hip/hip_runtime.h>

typedef _Float16 f16;
typedef __attribute__((ext_vector_type(8))) _Float16 f16x8;
typedef __attribute__((ext_vector_type(4))) _Float16 f16x4;
typedef __attribute__((ext_vector_type(4))) float f32x4;

#define MFMA16(a, b, c) __builtin_amdgcn_mfma_f32_16x16x32_f16((a), (b), (c), 0, 0, 0)

// async global->LDS, 16B per lane. LDS base must be WAVE-UNIFORM; HW scatters
// lane i's 16B to base + i*16 (m97/m104).
__device__ __forceinline__ void gld_lds16(const void* g, void* l) {
  __builtin_amdgcn_global_load_lds(
      (__attribute__((address_space(1))) void*)const_cast<void*>(g),
      (__attribute__((address_space(3))) void*)l, 16, 0, 0);
}

__device__ __forceinline__ f16x8 ld8(const f16* p) { return *(const f16x8*)p; }

// ---------------- fused cvt: z<3 -> X fp32->fp16; z==3 -> W transposes -------
__global__ __launch_bounds__(256) void cvt_all_kernel(
    const float* __restrict__ Q, const float* __restrict__ K, const float* __restrict__ V,
    f16* __restrict__ oq, f16* __restrict__ ok, f16* __restrict__ ov,
    const float* __restrict__ Wq, const float* __restrict__ Wk,
    const float* __restrict__ Wv, const float* __restrict__ Wo,
    f16* __restrict__ Tq, f16* __restrict__ Tk, f16* __restrict__ Tv, f16* __restrict__ To) {
  __shared__ float tile[64][65];
  if (blockIdx.z < 3) {
    const float* src = blockIdx.z == 0 ? Q : (blockIdx.z == 1 ? K : V);
    f16* dst = blockIdx.z == 0 ? oq : (blockIdx.z == 1 ? ok : ov);
    size_t i = ((size_t)blockIdx.x * 256 + threadIdx.x) * 4;
    float4 f = *(const float4*)(src + i);
    f16x4 o4;
    o4.x = (f16)f.x; o4.y = (f16)f.y; o4.z = (f16)f.z; o4.w = (f16)f.w;
    *(f16x4*)(dst + i) = o4;
    return;
  }
  if (blockIdx.x >= 1024) return;
  const int zz = blockIdx.x >> 8;
  const float* W = zz == 0 ? Wq : (zz == 1 ? Wk : (zz == 2 ? Wv : Wo));
  f16* T = zz == 0 ? Tq : (zz == 1 ? Tk : (zz == 2 ? Tv : To));
  const int tidx = blockIdx.x & 255;
  const int k0 = (tidx & 15) * 64, n0 = (tidx >> 4) * 64;
  const int tx = threadIdx.x & 63, ty = threadIdx.x >> 6;
#pragma unroll
  for (int rr = 0; rr < 16; ++rr) {
    int r = rr * 4 + ty;
    tile[r][tx] = W[(size_t)(k0 + r) * 1024 + n0 + tx];
  }
  __syncthreads();
#pragma unroll
  for (int rr = 0; rr < 16; ++rr) {
    int nn = rr * 4 + ty;
    T[(size_t)(n0 + nn) * 1024 + k0 + tx] = (f16)tile[tx][nn];
  }
}

// ---------------- QKV GEMM -- baseline-exact (proven 49us local optimum) -----
template <bool QKV>
__global__ __launch_bounds__(256) void gemm_bt_kernel(
    const f16* __restrict__ A0, const f16* __restrict__ A1, const f16* __restrict__ A2,
    const f16* __restrict__ B0, const f16* __restrict__ B1, const f16* __restrict__ B2,
    const float* __restrict__ bias0, const float* __restrict__ bias1, const float* __restrict__ bias2,
    f16* __restrict__ C0, f16* __restrict__ C1, f16* __restrict__ C2,
    f16* __restrict__ C3, float* __restrict__ Cf) {
  const int z = blockIdx.z;
  const f16* A = z == 0 ? A0 : (z == 1 ? A1 : A2);
  const f16* Bt = z == 0 ? B0 : (z == 1 ? B1 : B2);
  const float* bias = z == 0 ? bias0 : (z == 1 ? bias1 : bias2);

  __shared__ alignas(16) f16 lA[128 * 32];
  __shared__ alignas(16) f16 lB[128 * 32];

  const int t = threadIdx.x;
  const int w = t >> 6, lane = t & 63, quad = lane >> 4, l15 = lane & 15;
  const int wm = w >> 1, wn = w & 1;
  const int mbase = blockIdx.x * 128;
  const int nbase = blockIdx.y * 128;

  const f32x4 zero4 = {0.f, 0.f, 0.f, 0.f};
  f32x4 acc[4][4];
#pragma unroll
  for (int mi = 0; mi < 4; ++mi)
#pragma unroll
    for (int ni = 0; ni < 4; ++ni) acc[mi][ni] = zero4;

  const int r = t >> 2;
  const int koff = (t & 3) * 8;

  for (int k0 = 0; k0 < 1024; k0 += 32) {
    __syncthreads();
    gld_lds16(A + (size_t)(mbase + r) * 1024 + k0 + koff, (char*)lA + w * 1024);
    gld_lds16(A + (size_t)(mbase + 64 + r) * 1024 + k0 + koff, (char*)lA + 4096 + w * 1024);
    gld_lds16(Bt + (size_t)(nbase + r) * 1024 + k0 + koff, (char*)lB + w * 1024);
    gld_lds16(Bt + (size_t)(nbase + 64 + r) * 1024 + k0 + koff, (char*)lB + 4096 + w * 1024);
    __syncthreads();

    f16x8 af[4], bf[4];
#pragma unroll
    for (int mi = 0; mi < 4; ++mi)
      af[mi] = ld8(&lA[(wm * 64 + mi * 16 + l15) * 32 + quad * 8]);
#pragma unroll
    for (int ni = 0; ni < 4; ++ni)
      bf[ni] = ld8(&lB[(wn * 64 + ni * 16 + l15) * 32 + quad * 8]);
#pragma unroll
    for (int mi = 0; mi < 4; ++mi)
#pragma unroll
      for (int ni = 0; ni < 4; ++ni)
        acc[mi][ni] = MFMA16(af[mi], bf[ni], acc[mi][ni]);
  }

  // epilogue. C/D layout: col=lane&15, row=quad*4+reg (m89/m91).
#pragma unroll
  for (int mi = 0; mi < 4; ++mi) {
#pragma unroll
    for (int ni = 0; ni < 4; ++ni) {
#pragma unroll
      for (int rg = 0; rg < 4; ++rg) {
        const int row = mbase + wm * 64 + mi * 16 + quad * 4 + rg;
        const int col = nbase + wn * 64 + ni * 16 + l15;
        const float v = acc[mi][ni][rg] + bias[col];
        if (QKV) {
          const int bh = (row >> 10) * 16 + (col >> 6);
          const int s = row & 1023, d = col & 63;
          const f16 hv = (f16)v;
          if (z != 2) {
            f16* Ch = (z == 0) ? C0 : C1;
            Ch[(size_t)bh * 65536 + s * 64 + d] = hv;
          } else {
            C2[(size_t)bh * 65536 + s * 64 + d] = hv;
            // vtg: class r = s&3, class-pos n = s>>2; 64-block swizzle
            // n -> (n&15)*4 + ((n&63)>>4) so P stores / B-frag reads vectorize.
            const int rr = s & 3, n = s >> 2, wi = n & 63;
            C3[(size_t)bh * 65536 + (size_t)rr * 16384 + (size_t)d * 256 +
               (n & ~63) + ((wi & 15) << 2) + (wi >> 4)] = hv;
          }
        } else {
          Cf[(size_t)row * 1024 + col] = v;
        }
      }
    }
  }
}

// ---------------- out-projection GEMM: 64x128 tile, 512 blocks (baseline) ----
__global__ __launch_bounds__(256) void gemm_out_kernel(
    const f16* __restrict__ A, const f16* __restrict__ Bt,
    const float* __restrict__ bias, float* __restrict__ Cf) {
  __shared__ alignas(16) f16 lA[64 * 32];
  __shared__ alignas(16) f16 lB[128 * 32];

  const int t = threadIdx.x;
  const int w = t >> 6, lane = t & 63, quad = lane >> 4, l15 = lane & 15;
  const int wm = w >> 1, wn = w & 1;  // wave tile 32m x 64n
  const int mbase = blockIdx.x * 64;
  const int nbase = blockIdx.y * 128;

  const f32x4 zero4 = {0.f, 0.f, 0.f, 0.f};
  f32x4 acc[2][4];
#pragma unroll
  for (int mi = 0; mi < 2; ++mi)
#pragma unroll
    for (int ni = 0; ni < 4; ++ni) acc[mi][ni] = zero4;

  const int r = t >> 2;
  const int koff = (t & 3) * 8;

  for (int k0 = 0; k0 < 1024; k0 += 32) {
    __syncthreads();
    gld_lds16(A + (size_t)(mbase + r) * 1024 + k0 + koff, (char*)lA + w * 1024);
    gld_lds16(Bt + (size_t)(nbase + r) * 1024 + k0 + koff, (char*)lB + w * 1024);
    gld_lds16(Bt + (size_t)(nbase + 64 + r) * 1024 + k0 + koff, (char*)lB + 4096 + w * 1024);
    __syncthreads();

    f16x8 af[2], bf[4];
#pragma unroll
    for (int mi = 0; mi < 2; ++mi)
      af[mi] = ld8(&lA[(wm * 32 + mi * 16 + l15) * 32 + quad * 8]);
#pragma unroll
    for (int ni = 0; ni < 4; ++ni)
      bf[ni] = ld8(&lB[(wn * 64 + ni * 16 + l15) * 32 + quad * 8]);
#pragma unroll
    for (int mi = 0; mi < 2; ++mi)
#pragma unroll
      for (int ni = 0; ni < 4; ++ni)
        acc[mi][ni] = MFMA16(af[mi], bf[ni], acc[mi][ni]);
  }

#pragma unroll
  for (int mi = 0; mi < 2; ++mi)
#pragma unroll
    for (int ni = 0; ni < 4; ++ni)
#pragma unroll
      for (int rg = 0; rg < 4; ++rg) {
        const int row = mbase + wm * 32 + mi * 16 + quad * 4 + rg;
        const int col = nbase + wn * 64 + ni * 16 + l15;
        Cf[(size_t)row * 1024 + col] = acc[mi][ni][rg] + bias[col];
      }
}

// ---------------- far-field attention: 16-row waves (2x occupancy) -----------
// R5 had 2048 waves = 2 waves/SIMD for a latency-bound shfl/exp chain. Split
// each 32-row wave into two 16-row waves: 4096 waves = 4/SIMD. Extra K/V tile
// re-reads are L2-resident (128KB/head). + T5 setprio around MFMA clusters
// (barrier-free phase-diverse waves = the m191 regime).
__global__ __launch_bounds__(256) void attn_far_kernel(
    const f16* __restrict__ qh, const f16* __restrict__ kh,
    const f16* __restrict__ vtg, float* __restrict__ po, float* __restrict__ ml) {
  const int t = threadIdx.x;
  const int w = t >> 6, lane = t & 63, quad = lane >> 4, l15 = lane & 15;
  const int widx = blockIdx.x + 1024 * w;   // 0..4095
  const int bh = (widx & 255) >> 2, r = widx & 3;
  const int wq = widx >> 8;          // 0..15, 16 class-rows each
  const int m0 = wq * 16;
  const int ntiles = (wq >> 2) + 1;  // key tiles covering n <= m0+15

  __shared__ alignas(16) f16 lp[4][16 * 72];

  const f16* qb = qh + (size_t)bh * 65536;
  const f16* kb = kh + (size_t)bh * 65536;
  const f16* vb = vtg + (size_t)bh * 65536 + (size_t)r * 16384;  // [d][swz n]
  const float SCL2 = 0.125f * 1.44269504f;  // 1/sqrt(64) * log2(e)

  f16x8 aq[2];
  {
    const int i = 4 * (m0 + l15) + r;
#pragma unroll
    for (int ko = 0; ko < 2; ++ko)
      aq[ko] = ld8(qb + (size_t)i * 64 + ko * 32 + quad * 8);
  }

  const f32x4 zero4 = {0.f, 0.f, 0.f, 0.f};
  f32x4 o[4];
  float mrun[4], lrun[4];
#pragma unroll
  for (int i = 0; i < 4; ++i) {
    o[i] = zero4; mrun[i] = -1e30f; lrun[i] = 0.f;
  }

  for (int jt = 0; jt < ntiles; ++jt) {
    const int n0 = jt * 64;
    f16x8 bk0[4], bk1[4], bv0[4], bv1[4];
#pragma unroll
    for (int nt = 0; nt < 4; ++nt) {
      const f16* kr = kb + (size_t)(4 * (n0 + nt * 16 + l15) + r) * 64;
      bk0[nt] = ld8(kr + quad * 8);
      bk1[nt] = ld8(kr + 32 + quad * 8);
      const f16* vr = vb + (size_t)(nt * 16 + l15) * 256 + n0;  // swizzled keys
      bv0[nt] = ld8(vr + quad * 8);
      bv1[nt] = ld8(vr + 32 + quad * 8);
    }
    const bool lastt = (jt == ntiles - 1);  // only tile needing the n<=m mask
    f32x4 sc[4];
    __builtin_amdgcn_s_setprio(1);
#pragma unroll
    for (int nt = 0; nt < 4; ++nt) {
      f32x4 c = MFMA16(aq[0], bk0[nt], zero4);
      sc[nt] = MFMA16(aq[1], bk1[nt], c);
    }
    __builtin_amdgcn_s_setprio(0);
#pragma unroll
    for (int rg = 0; rg < 4; ++rg) {
      const int m = m0 + quad * 4 + rg;
      float s[4];
#pragma unroll
      for (int nt = 0; nt < 4; ++nt) {
        float vsc = sc[nt][rg] * SCL2;
        // <= m: self key (d=0) handled here; diag kernel does d=1..3.
        if (lastt) vsc = (n0 + nt * 16 + l15 <= m) ? vsc : -3.0e38f;
        s[nt] = vsc;
      }
      float tm = fmaxf(fmaxf(s[0], s[1]), fmaxf(s[2], s[3]));
      tm = fmaxf(tm, __shfl_xor(tm, 1));
      tm = fmaxf(tm, __shfl_xor(tm, 2));
      tm = fmaxf(tm, __shfl_xor(tm, 4));
      tm = fmaxf(tm, __shfl_xor(tm, 8));
      const float mnew = fmaxf(mrun[rg], tm);
      const float alpha = exp2f(mrun[rg] - mnew);
      float p[4], ps = 0.f;
#pragma unroll
      for (int nt = 0; nt < 4; ++nt) { p[nt] = exp2f(s[nt] - mnew); ps += p[nt]; }
      ps += __shfl_xor(ps, 1);
      ps += __shfl_xor(ps, 2);
      ps += __shfl_xor(ps, 4);
      ps += __shfl_xor(ps, 8);
      lrun[rg] = lrun[rg] * alpha + ps;
      mrun[rg] = mnew;
#pragma unroll
      for (int ntv = 0; ntv < 4; ++ntv) o[ntv][rg] *= alpha;
      f16x4 pk;
      pk.x = (f16)p[0]; pk.y = (f16)p[1]; pk.z = (f16)p[2]; pk.w = (f16)p[3];
      *(f16x4*)&lp[w][(quad * 4 + rg) * 72 + l15 * 4] = pk;
    }
    // PV (same-wave LDS produce->consume; compiler inserts lgkmcnt)
    {
      const f16x8 ap0 = ld8(&lp[w][l15 * 72 + quad * 8]);
      const f16x8 ap1 = ld8(&lp[w][l15 * 72 + 32 + quad * 8]);
      __builtin_amdgcn_s_setprio(1);
#pragma unroll
      for (int ntv = 0; ntv < 4; ++ntv) {
        f32x4 c = MFMA16(ap0, bv0[ntv], o[ntv]);
        o[ntv] = MFMA16(ap1, bv1[ntv], c);
      }
      __builtin_amdgcn_s_setprio(0);
    }
  }

  // write unnormalized partials (merged by attn_diag_kernel)
#pragma unroll
  for (int rg = 0; rg < 4; ++rg) {
    const int i = 4 * (m0 + quad * 4 + rg) + r;
    const size_t idx = (size_t)bh * 1024 + i;
#pragma unroll
    for (int ntv = 0; ntv < 4; ++ntv)
      po[idx * 64 + ntv * 16 + l15] = o[ntv][rg];
    if (l15 == 0) { ml[idx * 2] = mrun[rg]; ml[idx * 2 + 1] = lrun[rg]; }
  }
}

// ---------------- diagonal band (d=1..3) + merge, VECTORIZED -----------------
// 8 lanes per row (ri=lane>>3 row-in-group, c8=lane&7 d-chunk). All loads
// f16x8/float4 (16-32B/lane, G13); dot reduce = 3 shfls in the 8-lane group
// (was 6 across 64); one rcp replaces 8 divides. 8 rows/wave, 32 rows/block.
__global__ __launch_bounds__(256) void attn_diag_kernel(
    const f16* __restrict__ qh, const f16* __restrict__ kh, const f16* __restrict__ vh,
    const float* __restrict__ po, const float* __restrict__ ml, f16* __restrict__ ao) {
  const int t = threadIdx.x;
  const int w = t >> 6, lane = t & 63;
  const int ri = lane >> 3, c8 = lane & 7;
  const int g = blockIdx.x * 4 + w;       // 8-row group id, 0..8191
  const int bh = g >> 7;
  const int i = ((g & 127) << 3) + ri;    // 0..1023
  const float SCL2 = 0.125f * 1.44269504f;

  const size_t rb = (size_t)bh * 65536;
  const f16x8 q8 = ld8(qh + rb + (size_t)i * 64 + c8 * 8);
  float qf[8];
#pragma unroll
  for (int e = 0; e < 8; ++e) qf[e] = (float)q8[e];

  float s[3];
  f16x8 v8[3];
#pragma unroll
  for (int d = 1; d <= 3; ++d) {
    const int j = i - d;
    const int jc = j < 0 ? 0 : j;
    const f16x8 k8 = ld8(kh + rb + (size_t)jc * 64 + c8 * 8);
    v8[d - 1] = ld8(vh + rb + (size_t)jc * 64 + c8 * 8);
    float pr = 0.f;
#pragma unroll
    for (int e = 0; e < 8; ++e) pr = fmaf(qf[e], (float)k8[e], pr);
    pr += __shfl_xor(pr, 1);
    pr += __shfl_xor(pr, 2);
    pr += __shfl_xor(pr, 4);
    s[d - 1] = (j >= 0) ? pr * SCL2 : -3.0e38f;
  }
  const float md = fmaxf(fmaxf(s[0], s[1]), s[2]);
  const size_t idx = (size_t)bh * 1024 + i;
  const float2 mlv = *(const float2*)(ml + idx * 2);
  const float mf = mlv.x, lf = mlv.y;
  const float M = fmaxf(md, mf);  // mf finite for every i (self key in far)
  float p[3], ld = 0.f;
#pragma unroll
  for (int d = 0; d < 3; ++d) { p[d] = exp2f(s[d] - M); ld += p[d]; }
  const float fs = exp2f(mf - M);
  const float inv = 1.0f / (lf * fs + ld);
  const float4 po0 = *(const float4*)(po + idx * 64 + c8 * 8);
  const float4 po1 = *(const float4*)(po + idx * 64 + c8 * 8 + 4);
  float pe[8] = {po0.x, po0.y, po0.z, po0.w, po1.x, po1.y, po1.z, po1.w};
  f16x8 r8;
#pragma unroll
  for (int e = 0; e < 8; ++e) {
    const float ov = p[0] * (float)v8[0][e] + p[1] * (float)v8[1][e] +
                     p[2] * (float)v8[2][e];
    r8[e] = (f16)((pe[e] * fs + ov) * inv);
  }
  const int b = bh >> 4, h = bh & 15;
  *(f16x8*)(ao + ((size_t)(b * 1024 + i)) * 1024 + h * 64 + c8 * 8) = r8;
}

// ---------------------------------------------------------------------------
extern "C" void kernel_launch(void* const* d_in, const int* in_sizes, int n_in,
                              void* d_out, int out_size, void* d_ws, size_t ws_size,
                              hipStream_t stream) {
  const float* Q = (const float*)d_in[0];
  const float* K = (const float*)d_in[1];
  const float* V = (const float*)d_in[2];
  const float* Wq = (const float*)d_in[3];
  const float* bq = (const float*)d_in[4];
  const float* Wk = (const float*)d_in[5];
  const float* bk = (const float*)d_in[6];
  const float* Wv = (const float*)d_in[7];
  const float* bv = (const float*)d_in[8];
  const float* Wo = (const float*)d_in[9];
  const float* bo = (const float*)d_in[10];
  float* out = (float*)d_out;

  char* ws = (char*)d_ws;
  const size_t MB = 1ull << 20;
  f16* Xq  = (f16*)(ws + 0 * MB);
  f16* Xk  = (f16*)(ws + 8 * MB);
  f16* Xv  = (f16*)(ws + 16 * MB);
  f16* TWq = (f16*)(ws + 24 * MB);
  f16* TWk = (f16*)(ws + 26 * MB);
  f16* TWv = (f16*)(ws + 28 * MB);
  f16* TWo = (f16*)(ws + 30 * MB);
  f16* qhb = (f16*)(ws + 32 * MB);
  f16* khb = (f16*)(ws + 40 * MB);
  f16* vhb = (f16*)(ws + 48 * MB);
  f16* vtg = (f16*)(ws + 56 * MB);
  float* po  = (float*)(ws + 0 * MB);
  float* mlb = (float*)(ws + 16 * MB);
  f16* aob   = (f16*)(ws + 17 * MB);

  cvt_all_kernel<<<dim3(4096, 1, 4), 256, 0, stream>>>(
      Q, K, V, Xq, Xk, Xv, Wq, Wk, Wv, Wo, TWq, TWk, TWv, TWo);
  gemm_bt_kernel<true><<<dim3(32, 8, 3), 256, 0, stream>>>(
      Xq, Xk, Xv, TWq, TWk, TWv, bq, bk, bv, qhb, khb, vhb, vtg, nullptr);
  attn_far_kernel<<<dim3(1024), 256, 0, stream>>>(qhb, khb, vtg, po, mlb);
  attn_diag_kernel<<<dim3(2048), 256, 0, stream>>>(qhb, khb, vhb, po, mlb, aob);
  gemm_out_kernel<<<dim3(64, 8), 256, 0, stream>>>(aob, TWo, bo, out);
}

// Round 7
// 214.994 us; speedup vs baseline: 1.0067x; 1.0067x over previous
//
#include <hip/hip_runtime.h>

typedef _Float16 f16;
typedef __attribute__((ext_vector_type(8))) _Float16 f16x8;
typedef __attribute__((ext_vector_type(4))) _Float16 f16x4;
typedef __attribute__((ext_vector_type(4))) float f32x4;

#define MFMA16(a, b, c) __builtin_amdgcn_mfma_f32_16x16x32_f16((a), (b), (c), 0, 0, 0)

// async global->LDS, 16B per lane. LDS base must be WAVE-UNIFORM; HW scatters
// lane i's 16B to base + i*16 (m97/m104).
__device__ __forceinline__ void gld_lds16(const void* g, void* l) {
  __builtin_amdgcn_global_load_lds(
      (__attribute__((address_space(1))) void*)const_cast<void*>(g),
      (__attribute__((address_space(3))) void*)l, 16, 0, 0);
}

__device__ __forceinline__ f16x8 ld8(const f16* p) { return *(const f16x8*)p; }

// ---------------- fused cvt: z<3 -> X fp32->fp16; z==3 -> W transposes -------
__global__ __launch_bounds__(256) void cvt_all_kernel(
    const float* __restrict__ Q, const float* __restrict__ K, const float* __restrict__ V,
    f16* __restrict__ oq, f16* __restrict__ ok, f16* __restrict__ ov,
    const float* __restrict__ Wq, const float* __restrict__ Wk,
    const float* __restrict__ Wv, const float* __restrict__ Wo,
    f16* __restrict__ Tq, f16* __restrict__ Tk, f16* __restrict__ Tv, f16* __restrict__ To) {
  __shared__ float tile[64][65];
  if (blockIdx.z < 3) {
    const float* src = blockIdx.z == 0 ? Q : (blockIdx.z == 1 ? K : V);
    f16* dst = blockIdx.z == 0 ? oq : (blockIdx.z == 1 ? ok : ov);
    size_t i = ((size_t)blockIdx.x * 256 + threadIdx.x) * 4;
    float4 f = *(const float4*)(src + i);
    f16x4 o4;
    o4.x = (f16)f.x; o4.y = (f16)f.y; o4.z = (f16)f.z; o4.w = (f16)f.w;
    *(f16x4*)(dst + i) = o4;
    return;
  }
  if (blockIdx.x >= 1024) return;
  const int zz = blockIdx.x >> 8;
  const float* W = zz == 0 ? Wq : (zz == 1 ? Wk : (zz == 2 ? Wv : Wo));
  f16* T = zz == 0 ? Tq : (zz == 1 ? Tk : (zz == 2 ? Tv : To));
  const int tidx = blockIdx.x & 255;
  const int k0 = (tidx & 15) * 64, n0 = (tidx >> 4) * 64;
  const int tx = threadIdx.x & 63, ty = threadIdx.x >> 6;
#pragma unroll
  for (int rr = 0; rr < 16; ++rr) {
    int r = rr * 4 + ty;
    tile[r][tx] = W[(size_t)(k0 + r) * 1024 + n0 + tx];
  }
  __syncthreads();
#pragma unroll
  for (int rr = 0; rr < 16; ++rr) {
    int nn = rr * 4 + ty;
    T[(size_t)(n0 + nn) * 1024 + k0 + tx] = (f16)tile[tx][nn];
  }
}

// ---------------- QKV GEMM -- baseline-exact (proven 49us local optimum) -----
template <bool QKV>
__global__ __launch_bounds__(256) void gemm_bt_kernel(
    const f16* __restrict__ A0, const f16* __restrict__ A1, const f16* __restrict__ A2,
    const f16* __restrict__ B0, const f16* __restrict__ B1, const f16* __restrict__ B2,
    const float* __restrict__ bias0, const float* __restrict__ bias1, const float* __restrict__ bias2,
    f16* __restrict__ C0, f16* __restrict__ C1, f16* __restrict__ C2,
    f16* __restrict__ C3, float* __restrict__ Cf) {
  const int z = blockIdx.z;
  const f16* A = z == 0 ? A0 : (z == 1 ? A1 : A2);
  const f16* Bt = z == 0 ? B0 : (z == 1 ? B1 : B2);
  const float* bias = z == 0 ? bias0 : (z == 1 ? bias1 : bias2);

  __shared__ alignas(16) f16 lA[128 * 32];
  __shared__ alignas(16) f16 lB[128 * 32];

  const int t = threadIdx.x;
  const int w = t >> 6, lane = t & 63, quad = lane >> 4, l15 = lane & 15;
  const int wm = w >> 1, wn = w & 1;
  const int mbase = blockIdx.x * 128;
  const int nbase = blockIdx.y * 128;

  const f32x4 zero4 = {0.f, 0.f, 0.f, 0.f};
  f32x4 acc[4][4];
#pragma unroll
  for (int mi = 0; mi < 4; ++mi)
#pragma unroll
    for (int ni = 0; ni < 4; ++ni) acc[mi][ni] = zero4;

  const int r = t >> 2;
  const int koff = (t & 3) * 8;

  for (int k0 = 0; k0 < 1024; k0 += 32) {
    __syncthreads();
    gld_lds16(A + (size_t)(mbase + r) * 1024 + k0 + koff, (char*)lA + w * 1024);
    gld_lds16(A + (size_t)(mbase + 64 + r) * 1024 + k0 + koff, (char*)lA + 4096 + w * 1024);
    gld_lds16(Bt + (size_t)(nbase + r) * 1024 + k0 + koff, (char*)lB + w * 1024);
    gld_lds16(Bt + (size_t)(nbase + 64 + r) * 1024 + k0 + koff, (char*)lB + 4096 + w * 1024);
    __syncthreads();

    f16x8 af[4], bf[4];
#pragma unroll
    for (int mi = 0; mi < 4; ++mi)
      af[mi] = ld8(&lA[(wm * 64 + mi * 16 + l15) * 32 + quad * 8]);
#pragma unroll
    for (int ni = 0; ni < 4; ++ni)
      bf[ni] = ld8(&lB[(wn * 64 + ni * 16 + l15) * 32 + quad * 8]);
#pragma unroll
    for (int mi = 0; mi < 4; ++mi)
#pragma unroll
      for (int ni = 0; ni < 4; ++ni)
        acc[mi][ni] = MFMA16(af[mi], bf[ni], acc[mi][ni]);
  }

  // epilogue. C/D layout: col=lane&15, row=quad*4+reg (m89/m91).
#pragma unroll
  for (int mi = 0; mi < 4; ++mi) {
#pragma unroll
    for (int ni = 0; ni < 4; ++ni) {
#pragma unroll
      for (int rg = 0; rg < 4; ++rg) {
        const int row = mbase + wm * 64 + mi * 16 + quad * 4 + rg;
        const int col = nbase + wn * 64 + ni * 16 + l15;
        const float v = acc[mi][ni][rg] + bias[col];
        if (QKV) {
          const int bh = (row >> 10) * 16 + (col >> 6);
          const int s = row & 1023, d = col & 63;
          const f16 hv = (f16)v;
          if (z != 2) {
            f16* Ch = (z == 0) ? C0 : C1;
            Ch[(size_t)bh * 65536 + s * 64 + d] = hv;
          } else {
            C2[(size_t)bh * 65536 + s * 64 + d] = hv;
            // vtg: class r = s&3, class-pos n = s>>2; 64-block swizzle
            // n -> (n&15)*4 + ((n&63)>>4) so P stores / B-frag reads vectorize.
            const int rr = s & 3, n = s >> 2, wi = n & 63;
            C3[(size_t)bh * 65536 + (size_t)rr * 16384 + (size_t)d * 256 +
               (n & ~63) + ((wi & 15) << 2) + (wi >> 4)] = hv;
          }
        } else {
          Cf[(size_t)row * 1024 + col] = v;
        }
      }
    }
  }
}

// ---------------- out-projection GEMM: 64x128 tile, 512 blocks (baseline) ----
__global__ __launch_bounds__(256) void gemm_out_kernel(
    const f16* __restrict__ A, const f16* __restrict__ Bt,
    const float* __restrict__ bias, float* __restrict__ Cf) {
  __shared__ alignas(16) f16 lA[64 * 32];
  __shared__ alignas(16) f16 lB[128 * 32];

  const int t = threadIdx.x;
  const int w = t >> 6, lane = t & 63, quad = lane >> 4, l15 = lane & 15;
  const int wm = w >> 1, wn = w & 1;  // wave tile 32m x 64n
  const int mbase = blockIdx.x * 64;
  const int nbase = blockIdx.y * 128;

  const f32x4 zero4 = {0.f, 0.f, 0.f, 0.f};
  f32x4 acc[2][4];
#pragma unroll
  for (int mi = 0; mi < 2; ++mi)
#pragma unroll
    for (int ni = 0; ni < 4; ++ni) acc[mi][ni] = zero4;

  const int r = t >> 2;
  const int koff = (t & 3) * 8;

  for (int k0 = 0; k0 < 1024; k0 += 32) {
    __syncthreads();
    gld_lds16(A + (size_t)(mbase + r) * 1024 + k0 + koff, (char*)lA + w * 1024);
    gld_lds16(Bt + (size_t)(nbase + r) * 1024 + k0 + koff, (char*)lB + w * 1024);
    gld_lds16(Bt + (size_t)(nbase + 64 + r) * 1024 + k0 + koff, (char*)lB + 4096 + w * 1024);
    __syncthreads();

    f16x8 af[2], bf[4];
#pragma unroll
    for (int mi = 0; mi < 2; ++mi)
      af[mi] = ld8(&lA[(wm * 32 + mi * 16 + l15) * 32 + quad * 8]);
#pragma unroll
    for (int ni = 0; ni < 4; ++ni)
      bf[ni] = ld8(&lB[(wn * 64 + ni * 16 + l15) * 32 + quad * 8]);
#pragma unroll
    for (int mi = 0; mi < 2; ++mi)
#pragma unroll
      for (int ni = 0; ni < 4; ++ni)
        acc[mi][ni] = MFMA16(af[mi], bf[ni], acc[mi][ni]);
  }

#pragma unroll
  for (int mi = 0; mi < 2; ++mi)
#pragma unroll
    for (int ni = 0; ni < 4; ++ni)
#pragma unroll
      for (int rg = 0; rg < 4; ++rg) {
        const int row = mbase + wm * 32 + mi * 16 + quad * 4 + rg;
        const int col = nbase + wn * 64 + ni * 16 + l15;
        Cf[(size_t)row * 1024 + col] = acc[mi][ni][rg] + bias[col];
      }
}

// ---------------- FUSED attention: far field + diag band + merge -------------
// Far part identical to R6 (16-row waves). Then the SAME wave computes its
// rows' d=1..3 scores via MFMA (B-frag col c = row holds K[i(c)-d]; diagonal
// extracted with one shfl per (d,rg) from lane quad*20+rg), merges in-register
// and writes aob directly. Deletes attn_diag kernel + the 45MB po/ml round
// trip; o never leaves registers (same or better precision than fp32 po).
__global__ __launch_bounds__(256) void attn_fused_kernel(
    const f16* __restrict__ qh, const f16* __restrict__ kh,
    const f16* __restrict__ vtg, const f16* __restrict__ vh,
    f16* __restrict__ ao) {
  const int t = threadIdx.x;
  const int w = t >> 6, lane = t & 63, quad = lane >> 4, l15 = lane & 15;
  const int widx = blockIdx.x + 1024 * w;   // 0..4095
  const int bh = (widx & 255) >> 2, r = widx & 3;
  const int wq = widx >> 8;          // 0..15, 16 class-rows each
  const int m0 = wq * 16;
  const int ntiles = (wq >> 2) + 1;  // key tiles covering n <= m0+15

  __shared__ alignas(16) f16 lp[4][16 * 72];

  const f16* qb = qh + (size_t)bh * 65536;
  const f16* kb = kh + (size_t)bh * 65536;
  const f16* vb = vtg + (size_t)bh * 65536 + (size_t)r * 16384;  // [d][swz n]
  const float SCL2 = 0.125f * 1.44269504f;  // 1/sqrt(64) * log2(e)

  f16x8 aq[2];
  {
    const int i = 4 * (m0 + l15) + r;
#pragma unroll
    for (int ko = 0; ko < 2; ++ko)
      aq[ko] = ld8(qb + (size_t)i * 64 + ko * 32 + quad * 8);
  }

  const f32x4 zero4 = {0.f, 0.f, 0.f, 0.f};
  f32x4 o[4];
  float mrun[4], lrun[4];
#pragma unroll
  for (int i = 0; i < 4; ++i) {
    o[i] = zero4; mrun[i] = -1e30f; lrun[i] = 0.f;
  }

  for (int jt = 0; jt < ntiles; ++jt) {
    const int n0 = jt * 64;
    f16x8 bk0[4], bk1[4], bv0[4], bv1[4];
#pragma unroll
    for (int nt = 0; nt < 4; ++nt) {
      const f16* kr = kb + (size_t)(4 * (n0 + nt * 16 + l15) + r) * 64;
      bk0[nt] = ld8(kr + quad * 8);
      bk1[nt] = ld8(kr + 32 + quad * 8);
      const f16* vr = vb + (size_t)(nt * 16 + l15) * 256 + n0;  // swizzled keys
      bv0[nt] = ld8(vr + quad * 8);
      bv1[nt] = ld8(vr + 32 + quad * 8);
    }
    const bool lastt = (jt == ntiles - 1);  // only tile needing the n<=m mask
    f32x4 sc[4];
    __builtin_amdgcn_s_setprio(1);
#pragma unroll
    for (int nt = 0; nt < 4; ++nt) {
      f32x4 c = MFMA16(aq[0], bk0[nt], zero4);
      sc[nt] = MFMA16(aq[1], bk1[nt], c);
    }
    __builtin_amdgcn_s_setprio(0);
#pragma unroll
    for (int rg = 0; rg < 4; ++rg) {
      const int m = m0 + quad * 4 + rg;
      float s[4];
#pragma unroll
      for (int nt = 0; nt < 4; ++nt) {
        float vsc = sc[nt][rg] * SCL2;
        // <= m: self key (d=0) handled here; diag part does d=1..3.
        if (lastt) vsc = (n0 + nt * 16 + l15 <= m) ? vsc : -3.0e38f;
        s[nt] = vsc;
      }
      float tm = fmaxf(fmaxf(s[0], s[1]), fmaxf(s[2], s[3]));
      tm = fmaxf(tm, __shfl_xor(tm, 1));
      tm = fmaxf(tm, __shfl_xor(tm, 2));
      tm = fmaxf(tm, __shfl_xor(tm, 4));
      tm = fmaxf(tm, __shfl_xor(tm, 8));
      const float mnew = fmaxf(mrun[rg], tm);
      const float alpha = exp2f(mrun[rg] - mnew);
      float p[4], ps = 0.f;
#pragma unroll
      for (int nt = 0; nt < 4; ++nt) { p[nt] = exp2f(s[nt] - mnew); ps += p[nt]; }
      ps += __shfl_xor(ps, 1);
      ps += __shfl_xor(ps, 2);
      ps += __shfl_xor(ps, 4);
      ps += __shfl_xor(ps, 8);
      lrun[rg] = lrun[rg] * alpha + ps;
      mrun[rg] = mnew;
#pragma unroll
      for (int ntv = 0; ntv < 4; ++ntv) o[ntv][rg] *= alpha;
      f16x4 pk;
      pk.x = (f16)p[0]; pk.y = (f16)p[1]; pk.z = (f16)p[2]; pk.w = (f16)p[3];
      *(f16x4*)&lp[w][(quad * 4 + rg) * 72 + l15 * 4] = pk;
    }
    // PV (same-wave LDS produce->consume; compiler inserts lgkmcnt)
    {
      const f16x8 ap0 = ld8(&lp[w][l15 * 72 + quad * 8]);
      const f16x8 ap1 = ld8(&lp[w][l15 * 72 + 32 + quad * 8]);
      __builtin_amdgcn_s_setprio(1);
#pragma unroll
      for (int ntv = 0; ntv < 4; ++ntv) {
        f32x4 c = MFMA16(ap0, bv0[ntv], o[ntv]);
        o[ntv] = MFMA16(ap1, bv1[ntv], c);
      }
      __builtin_amdgcn_s_setprio(0);
    }
  }

  // ---- diag band d=1..3 via MFMA (B col c = target row), shfl the diagonal --
  float sd[3][4];
#pragma unroll
  for (int d = 1; d <= 3; ++d) {
    f16x8 bd0, bd1;
    {
      int j = 4 * (m0 + l15) + r - d;
      if (j < 0) j = 0;  // masked below
      const f16* kr = kb + (size_t)j * 64;
      bd0 = ld8(kr + quad * 8);
      bd1 = ld8(kr + 32 + quad * 8);
    }
    f32x4 c = MFMA16(aq[0], bd0, zero4);
    c = MFMA16(aq[1], bd1, c);
#pragma unroll
    for (int rg = 0; rg < 4; ++rg) {
      // diagonal S[row][row] lives on lane quad*16 + (quad*4+rg), reg rg
      const float dv = __shfl(c[rg], quad * 20 + rg);
      const int i = 4 * (m0 + quad * 4 + rg) + r;
      sd[d - 1][rg] = (i >= d) ? dv * SCL2 : -3.0e38f;
    }
  }

  // ---- merge + write final output (no po/ml round trip) ----
  const f16* vhb2 = vh + (size_t)bh * 65536;
  const int b = bh >> 4, h = bh & 15;
#pragma unroll
  for (int rg = 0; rg < 4; ++rg) {
    const int i = 4 * (m0 + quad * 4 + rg) + r;
    const float mdg = fmaxf(fmaxf(sd[0][rg], sd[1][rg]), sd[2][rg]);
    const float M = fmaxf(mrun[rg], mdg);
    const float fs = exp2f(mrun[rg] - M);
    float p[3];
    float ltot = lrun[rg] * fs;
#pragma unroll
    for (int d = 0; d < 3; ++d) { p[d] = exp2f(sd[d][rg] - M); ltot += p[d]; }
    const float inv = 1.0f / ltot;
    const f16* v1 = vhb2 + (size_t)((i >= 1) ? i - 1 : 0) * 64;
    const f16* v2 = vhb2 + (size_t)((i >= 2) ? i - 2 : 0) * 64;
    const f16* v3 = vhb2 + (size_t)((i >= 3) ? i - 3 : 0) * 64;
    f16* aor = ao + ((size_t)(b * 1024 + i)) * 1024 + h * 64;
#pragma unroll
    for (int ntv = 0; ntv < 4; ++ntv) {
      const int dc = ntv * 16 + l15;
      const float ov = p[0] * (float)v1[dc] + p[1] * (float)v2[dc] +
                       p[2] * (float)v3[dc];
      aor[dc] = (f16)((o[ntv][rg] * fs + ov) * inv);
    }
  }
}

// ---------------------------------------------------------------------------
extern "C" void kernel_launch(void* const* d_in, const int* in_sizes, int n_in,
                              void* d_out, int out_size, void* d_ws, size_t ws_size,
                              hipStream_t stream) {
  const float* Q = (const float*)d_in[0];
  const float* K = (const float*)d_in[1];
  const float* V = (const float*)d_in[2];
  const float* Wq = (const float*)d_in[3];
  const float* bq = (const float*)d_in[4];
  const float* Wk = (const float*)d_in[5];
  const float* bk = (const float*)d_in[6];
  const float* Wv = (const float*)d_in[7];
  const float* bv = (const float*)d_in[8];
  const float* Wo = (const float*)d_in[9];
  const float* bo = (const float*)d_in[10];
  float* out = (float*)d_out;

  char* ws = (char*)d_ws;
  const size_t MB = 1ull << 20;
  f16* Xq  = (f16*)(ws + 0 * MB);
  f16* Xk  = (f16*)(ws + 8 * MB);
  f16* Xv  = (f16*)(ws + 16 * MB);
  f16* TWq = (f16*)(ws + 24 * MB);
  f16* TWk = (f16*)(ws + 26 * MB);
  f16* TWv = (f16*)(ws + 28 * MB);
  f16* TWo = (f16*)(ws + 30 * MB);
  f16* qhb = (f16*)(ws + 32 * MB);
  f16* khb = (f16*)(ws + 40 * MB);
  f16* vhb = (f16*)(ws + 48 * MB);
  f16* vtg = (f16*)(ws + 56 * MB);
  f16* aob = (f16*)(ws + 17 * MB);   // over dead Xv/TWq space (post-gemm)

  cvt_all_kernel<<<dim3(4096, 1, 4), 256, 0, stream>>>(
      Q, K, V, Xq, Xk, Xv, Wq, Wk, Wv, Wo, TWq, TWk, TWv, TWo);
  gemm_bt_kernel<true><<<dim3(32, 8, 3), 256, 0, stream>>>(
      Xq, Xk, Xv, TWq, TWk, TWv, bq, bk, bv, qhb, khb, vhb, vtg, nullptr);
  attn_fused_kernel<<<dim3(1024), 256, 0, stream>>>(qhb, khb, vtg, vhb, aob);
  gemm_out_kernel<<<dim3(64, 8), 256, 0, stream>>>(aob, TWo, bo, out);
}